// Round 20
// baseline (312.558 us; speedup 1.0000x reference)
//
#include <hip/hip_runtime.h>
#include <hip/hip_bf16.h>
#include <hip/hip_fp16.h>

#define NTOT 4194304
typedef __attribute__((ext_vector_type(4)))  short short4v;
typedef __attribute__((ext_vector_type(8)))  short short8v;
typedef __attribute__((ext_vector_type(4)))  float f32x4;
typedef __attribute__((ext_vector_type(2)))  float fx2;
typedef __attribute__((ext_vector_type(4)))  unsigned int uint4v;

__device__ __forceinline__ ushort f2bf(float f){
    __hip_bfloat16 h = __float2bfloat16(f);
    return __bfloat16_as_ushort(h);
}
__device__ __forceinline__ float bf2f(ushort u){
    return __uint_as_float(((unsigned)u)<<16);
}

// ---------------- weight pack: per-lane MFMA B-fragment order, bf16 ----------------
__global__ __launch_bounds__(256) void pack_w(
    const float* __restrict__ dw, const float* __restrict__ ow,
    ushort* __restrict__ dwPk, ushort* __restrict__ owPk,
    float* __restrict__ statsG)
{
    int i = blockIdx.x*256 + threadIdx.x;
    if (i < 286720) {
        int j = i&3, co = (i>>2)&63, jg=(i>>8)&1, cih=(i>>9)&1, koff=(i>>10)&1;
        int r = i>>11; int kkp = r%5; int r2 = r/5; int ciq = r2&3; int l = r2>>2;
        int kk = kkp*2+koff, ci = ciq*16 + cih*8 + jg*4 + j;
        float v = (kk<9)? dw[((l*64+co)*64+ci)*9+kk] : 0.f;
        dwPk[i] = f2bf(v);
    }
    if (i < 143360) {
        int j = i&3, co = (i>>2)&31, jg=(i>>7)&1, cih=(i>>8)&1, koff=(i>>9)&1;
        int r = i>>10; int kkp = r%5; int r2 = r/5; int ciq = r2&3; int l = r2>>2;
        int kk = kkp*2+koff, ci = ciq*16 + cih*8 + jg*4 + j;
        float v = (kk<9 && co<18)? ow[((l*18+co)*64+ci)*9+kk] : 0.f;
        owPk[i] = f2bf(v);
    }
    if (i < 7*1024) statsG[i] = 0.f;
}

// ---------------- one-time transpose: NCHW f32 -> [b][y][x][ci] bf16 ----------------
__global__ __launch_bounds__(256) void transpose_x(
    const float* __restrict__ src, ushort* __restrict__ xT)
{
    __shared__ ushort lds[128*72];
    const int bid = blockIdx.x, t = threadIdx.x;
    const int b = bid>>7, y = bid&127;
    const float* sp = src + (b<<20) + (y<<7);
#pragma unroll
    for (int i=0;i<32;i++){
        int lin = i*256 + t;
        int ci = lin>>7, xx = lin&127;
        lds[xx*72 + ci] = f2bf(sp[(ci<<14) + xx]);
    }
    __syncthreads();
    ushort* dp = xT + (((b<<7)+y)<<13);
#pragma unroll
    for (int i=0;i<4;i++){
        int u = i*256 + t;
        int xx = u>>3, cg = u&7;
        short8v v8 = *(const short8v*)(lds + xx*72 + cg*8);
        *(short8v*)(dp + (xx<<6) + cg*8) = v8;
    }
}

__constant__ int KHt[10] = {0,0,0,1,1,1,2,2,2,2};
__constant__ int KWt[10] = {0,1,2,0,1,2,0,1,2,2};

// ---------------- fused offset-conv + deformable conv ----------------
// r19 structure, staging 4x -> 2x:
//  - pass 1 (offset conv) reads A-frags DIRECTLY from global xT (L2-resident,
//    regular 3x3 pattern, b128 at 64B stride) -> no staging/LDS/barriers.
//  - pass 2 stages each 32-ci phase exactly once.
// Hoisted bilinear setup shared by both cil; lazy image masking; pk_fma interp.
__global__ __attribute__((amdgpu_flat_work_group_size(512,512), amdgpu_waves_per_eu(4,8)))
void dcn_layer(
    const ushort* __restrict__ xTA, const ushort* __restrict__ xTB,
    const ushort* __restrict__ owPkB, const float* __restrict__ obB,
    const ushort* __restrict__ dwPkB, ushort* __restrict__ ybA,
    ushort* __restrict__ ybX, float* __restrict__ statsB, int l0, int l1)
{
    __shared__ __align__(16) char smem[79360];
    __half* offh = (__half*)(smem + 69120);      // [256 px][20] fp16

    const int t = threadIdx.x, lane = t&63, w = t>>6;
    const int l15 = lane&15, lg = lane>>4;
    const int cih = lg&1, koff = lane>>5;
    const int bid = blockIdx.x;
    const int lsel = bid >> 8;
    const int tb = bid & 255;
    const int L = lsel ? l1 : l0;
    const ushort* owPk = owPkB + L*20480;
    const float*  ob   = obB   + L*18;
    const ushort* dwPk = dwPkB + L*40960;
    ushort* yb         = lsel ? ybX : ybA;
    float*  statsL     = statsB + L*1024;

    const int xcd = tb&7, idx = tb>>3;
    const int b = xcd>>1, vh = xcd&1;
    const int ht = vh*8 + (idx>>2), wt = idx&3;
    const int w0 = wt*32, h0 = ht*8;
    const int row = h0 + w;
    const int RLO = h0-5, CLO = w0-8;            // 18 x 48 halo
    const ushort* xb = (lsel ? xTB : xTA) + (b<<20);

    const short8v zz8 = (short8v){0,0,0,0,0,0,0,0};
    auto stage = [&](int P){
#pragma unroll 1
        for (int i=0;i<7;i++){
            int d = i*512 + t;
            if (d < 3456) {
                int slot = d&3, sp = d>>2;
                int rowt = sp/48, colt = sp - rowt*48;
                int gy = RLO+rowt, gx = CLO+colt;
                bool ok = ((unsigned)gy<128u) && ((unsigned)gx<128u);
                int gyc = min(max(gy,0),127), gxc = min(max(gx,0),127);
                short8v v = *(const short8v*)(xb + (((gyc<<7)+gxc)<<6) + (P*4+slot)*8);
                if (!ok) v = zz8;
                *(short8v*)(smem + sp*80 + ((slot^(sp&3))<<4)) = v;
            }
        }
    };

    // ================= pass 1: offset conv via MFMA (A direct from xT / L2) =================
    f32x4 oacc[2][2];
#pragma unroll
    for (int p=0;p<2;p++)
#pragma unroll
        for (int q=0;q<2;q++) oacc[p][q] = (f32x4){0.f,0.f,0.f,0.f};

#pragma unroll 1
    for (int kkp=0; kkp<5; ++kkp) {
        int kkA = 2*kkp;
        int kkB2 = (kkA+1>8)?8:(kkA+1);
        int kh = koff ? KHt[kkB2] : KHt[kkA];
        int kw = koff ? KWt[kkB2] : KWt[kkA];
        int gy = row + kh - 1;
        bool vy = ((unsigned)gy<128u);
        int gyc = min(max(gy,0),127);
        int ebase[2]; bool okp[2];
#pragma unroll
        for (int p=0;p<2;p++){
            int gx = w0 + p*16 + l15 + kw - 1;
            okp[p] = vy && ((unsigned)gx<128u);
            int gxc = min(max(gx,0),127);
            ebase[p] = (((gyc<<7)+gxc)<<6) + cih*8;
        }
#pragma unroll
        for (int ciq=0; ciq<4; ++ciq) {
            short8v afr[2];
#pragma unroll
            for (int p=0;p<2;p++){
                short8v q = *(const short8v*)(xb + ebase[p] + ciq*16);
                afr[p] = okp[p] ? q : zz8;
            }
            const ushort* wop = owPk + ciq*5120 + kkp*1024 + koff*512 + cih*256;
#pragma unroll
            for (int q2=0;q2<2;q2++){
                short4v b0 = *(const short4v*)(wop +       (q2*16+l15)*4);
                short4v b1 = *(const short4v*)(wop + 128 + (q2*16+l15)*4);
                short8v bb = __builtin_shufflevector(b0,b1,0,1,2,3,4,5,6,7);
#pragma unroll
                for (int p=0;p<2;p++)
                    oacc[p][q2] = __builtin_amdgcn_mfma_f32_16x16x32_bf16(afr[p], bb, oacc[p][q2], 0,0,0);
            }
        }
    }

    // redistribute offsets fp16: offh[pix 256][20]; only o<18
    {
        float biasq[2];
#pragma unroll
        for (int q=0;q<2;q++){ int o = q*16+l15; biasq[q] = (o<18)? ob[o] : 0.f; }
#pragma unroll
        for (int p=0;p<2;p++)
#pragma unroll
            for (int q=0;q<2;q++){
                int o = q*16+l15;
                if (o < 18) {
#pragma unroll
                    for (int r=0;r<4;r++){
                        int pix = w*32 + p*16 + lg*4 + r;
                        offh[pix*20 + o] = __float2half(oacc[p][q][r] + biasq[q]);
                    }
                }
            }
    }

    // ================= pass 2: deformable conv via MFMA (2 stages total) =================
    f32x4 acc[2][4];
#pragma unroll
    for (int p=0;p<2;p++)
#pragma unroll
        for (int q=0;q<4;q++) acc[p][q] = (f32x4){0.f,0.f,0.f,0.f};

#pragma unroll 1
    for (int P=0; P<2; ++P) {
        if (P) __syncthreads();    // prior phase tile reads done
        stage(P);
        __syncthreads();           // tile + (P==0) offh writes visible
#pragma unroll 1
        for (int kkp=0; kkp<5; ++kkp) {
            int kkA = 2*kkp;
            int kkB2 = (kkA+1>8)?8:(kkA+1);
            int kh = koff ? KHt[kkB2] : KHt[kkA];
            int kw = koff ? KWt[kkB2] : KWt[kkA];
            int kkX = koff ? kkB2 : kkA;
            // ---- hoisted bilinear setup (shared by both cil) ----
            float F00[2],F01[2],F10[2],F11[2];
            int PC0[2],PC1[2],PC2[2],PC3[2], M40[2],M41[2],M42[2],M43[2];
            bool FB[2];
#pragma unroll
            for (int p=0;p<2;p++){
                int pix = w*32 + p*16 + l15;
                unsigned odp = *(const unsigned*)((const char*)offh + pix*40 + 4*kkX);
                float dy = __half2float(__ushort_as_half((ushort)(odp & 0xffffu)));
                float dx = __half2float(__ushort_as_half((ushort)(odp >> 16)));
                float py = (float)(row + kh - 1) + dy;
                float px = (float)(w0 + p*16 + l15 + kw - 1) + dx;
                float fy = floorf(py), fx = floorf(px);
                float ly = py - fy, lx = px - fx;
                int y0 = (int)fy, x0 = (int)fx;
                int r0 = y0 - RLO, c0 = x0 - CLO;
                int r1 = r0 + 1,  c1 = c0 + 1;
                bool ty0 = ((unsigned)r0<18u), ty1 = ((unsigned)r1<18u);
                bool tx0 = ((unsigned)c0<48u), tx1 = ((unsigned)c1<48u);
                float w00 = (1.f-ly)*(1.f-lx), w01 = (1.f-ly)*lx;
                float w10 = ly*(1.f-lx),       w11 = ly*lx;
                F00[p] = (ty0&&tx0)? w00 : 0.f;
                F01[p] = (ty0&&tx1)? w01 : 0.f;
                F10[p] = (ty1&&tx0)? w10 : 0.f;
                F11[p] = (ty1&&tx1)? w11 : 0.f;
                int rc0 = min(max(r0,0),17), rc1 = min(max(r1,0),17);
                int xc0 = min(max(c0,0),47), xc1 = min(max(c1,0),47);
                int s00 = rc0*48+xc0, s01 = rc0*48+xc1, s10 = rc1*48+xc0, s11 = rc1*48+xc1;
                PC0[p]=s00*80; M40[p]=(s00&3)<<4;
                PC1[p]=s01*80; M41[p]=(s01&3)<<4;
                PC2[p]=s10*80; M42[p]=(s10&3)<<4;
                PC3[p]=s11*80; M43[p]=(s11&3)<<4;
                bool allIn = ty0 && ty1 && tx0 && tx1;
                FB[p] = !allIn && (y0>=-1)&&(y0<=127)&&(x0>=-1)&&(x0<=127);
            }
#pragma unroll
            for (int cil=0; cil<2; ++cil) {
                int ciq = P*2 + cil;
                int u4 = (((cil<<1)|cih)<<4);
                short8v afr[2];
#pragma unroll
                for (int p=0;p<2;p++){
                    uint4v q00 = *(const uint4v*)(smem + PC0[p] + (u4^M40[p]));
                    uint4v q01 = *(const uint4v*)(smem + PC1[p] + (u4^M41[p]));
                    uint4v q10 = *(const uint4v*)(smem + PC2[p] + (u4^M42[p]));
                    uint4v q11 = *(const uint4v*)(smem + PC3[p] + (u4^M43[p]));
                    fx2 Fa = {F00[p],F00[p]}, Fb = {F01[p],F01[p]};
                    fx2 Fc = {F10[p],F10[p]}, Fd = {F11[p],F11[p]};
                    fx2 sv2[4];
#pragma unroll
                    for (int k=0;k<4;k++){
                        fx2 xa = {__uint_as_float(q00[k]<<16), __uint_as_float(q00[k]&0xffff0000u)};
                        fx2 xb2= {__uint_as_float(q01[k]<<16), __uint_as_float(q01[k]&0xffff0000u)};
                        fx2 xc = {__uint_as_float(q10[k]<<16), __uint_as_float(q10[k]&0xffff0000u)};
                        fx2 xd = {__uint_as_float(q11[k]<<16), __uint_as_float(q11[k]&0xffff0000u)};
                        sv2[k] = xa*Fa + xb2*Fb + xc*Fc + xd*Fd;   // v_pk_fma_f32
                    }
                    if (__builtin_expect(FB[p], 0)) {
                        // rare out-of-tile: recompute locally (execz-skipped)
                        int pix = w*32 + p*16 + l15;
                        unsigned odp = *(const unsigned*)((const char*)offh + pix*40 + 4*kkX);
                        float dy = __half2float(__ushort_as_half((ushort)(odp & 0xffffu)));
                        float dx = __half2float(__ushort_as_half((ushort)(odp >> 16)));
                        float py = (float)(row + kh - 1) + dy;
                        float px = (float)(w0 + p*16 + l15 + kw - 1) + dx;
                        float fy = floorf(py), fx = floorf(px);
                        float ly = py - fy, lx = px - fx;
                        int y0 = (int)fy, x0 = (int)fx;
                        int r0 = y0 - RLO, c0 = x0 - CLO;
                        bool ty0 = ((unsigned)r0<18u), ty1 = ((unsigned)(r0+1)<18u);
                        bool tx0 = ((unsigned)c0<48u), tx1 = ((unsigned)(c0+1)<48u);
                        bool vy0 = ((unsigned)y0<128u), vy1 = ((unsigned)(y0+1)<128u);
                        bool vx0 = ((unsigned)x0<128u), vx1 = ((unsigned)(x0+1)<128u);
                        float w00 = (1.f-ly)*(1.f-lx), w01 = (1.f-ly)*lx;
                        float w10 = ly*(1.f-lx),       w11 = ly*lx;
                        float rw00 = (vy0&&vx0&&!(ty0&&tx0))? w00 : 0.f;
                        float rw01 = (vy0&&vx1&&!(ty0&&tx1))? w01 : 0.f;
                        float rw10 = (vy1&&vx0&&!(ty1&&tx0))? w10 : 0.f;
                        float rw11 = (vy1&&vx1&&!(ty1&&tx1))? w11 : 0.f;
                        int y0c=min(max(y0,0),127), y1c=min(max(y0+1,0),127);
                        int x0c=min(max(x0,0),127), x1c=min(max(x0+1,0),127);
                        int cofs = (ciq*2 + cih)*8;
                        short8v a0 = *(const short8v*)(xb + ((((y0c<<7)+x0c)<<6) + cofs));
                        short8v a1 = *(const short8v*)(xb + ((((y0c<<7)+x1c)<<6) + cofs));
                        short8v a2 = *(const short8v*)(xb + ((((y1c<<7)+x0c)<<6) + cofs));
                        short8v a3 = *(const short8v*)(xb + ((((y1c<<7)+x1c)<<6) + cofs));
#pragma unroll
                        for (int j=0;j<8;j++){
                            float add = rw00*bf2f((ushort)a0[j]) + rw01*bf2f((ushort)a1[j])
                                      + rw10*bf2f((ushort)a2[j]) + rw11*bf2f((ushort)a3[j]);
                            if (j&1) sv2[j>>1].y += add; else sv2[j>>1].x += add;
                        }
                    }
#pragma unroll
                    for (int k=0;k<4;k++){
                        afr[p][2*k]   = (short)f2bf(sv2[k].x);
                        afr[p][2*k+1] = (short)f2bf(sv2[k].y);
                    }
                }
                const ushort* wp = dwPk + ciq*10240 + kkp*2048 + koff*1024 + cih*512;
#pragma unroll
                for (int q=0;q<4;q++){
                    short4v b0 = *(const short4v*)(wp +       (q*16+l15)*4);
                    short4v b1 = *(const short4v*)(wp + 256 + (q*16+l15)*4);
                    short8v bb = __builtin_shufflevector(b0,b1,0,1,2,3,4,5,6,7);
                    acc[0][q] = __builtin_amdgcn_mfma_f32_16x16x32_bf16(afr[0], bb, acc[0][q], 0,0,0);
                    acc[1][q] = __builtin_amdgcn_mfma_f32_16x16x32_bf16(afr[1], bb, acc[1][q], 0,0,0);
                }
            }
        }
    }

    // ================= epilogue: LDS transpose, bf16 store, stats =================
    float* yt  = (float*)smem;               // [32 co][260] f32 (overlays tile)
    float* red = (float*)(smem + 33280);     // 1024 f32
#pragma unroll
    for (int half=0; half<2; ++half){
        __syncthreads();
#pragma unroll
        for (int p=0;p<2;p++)
#pragma unroll
            for (int qq=0;qq<2;qq++)
                *(f32x4*)(yt + (qq*16+l15)*260 + w*32 + p*16 + lg*4) = acc[p][half*2+qq];
        __syncthreads();
#pragma unroll
        for (int i=0;i<2;i++){
            int u = i*512 + t;
            int co = u>>5, px8 = (u&31)*8;
            short8v v8;
#pragma unroll
            for (int e=0;e<8;e++) v8[e] = (short)f2bf(yt[co*260 + px8 + e]);
            *(short8v*)(yb + ((((b<<6) + half*32 + co)<<14)
                        + ((h0 + (px8>>5))<<7) + w0 + (px8&31))) = v8;
        }
        {
            float s=0.f, s2=0.f;
            int co = t&31, seg = t>>5;
            const float* bp = yt + co*260 + seg*16;
#pragma unroll
            for (int qd=0;qd<16;qd++){ float v = bp[qd]; s += v; s2 += v*v; }
            red[seg*32+co] = s; red[512 + seg*32+co] = s2;
        }
        __syncthreads();
        if (t < 64){
            int vv = t>>5, cc = t&31;
            float a = 0.f;
#pragma unroll
            for (int g=0;g<16;g++) a += red[vv*512 + g*32 + cc];
            atomicAdd(statsL + (tb&7)*128 + vv*64 + half*32 + cc, a);
        }
    }
}

// ---------------- fused normalize + ReLU + epilogue + xT emission ----------------
// mode bits: 1=write dstF f32, 2=add addB (bf16 NCHW), 4=accum dstF f32,
//            8=emit xT, 16=write dstB (bf16 NCHW).
__global__ __launch_bounds__(256) void norm_fuse(
    const ushort* __restrict__ yv, const float* __restrict__ statsL,
    const float* __restrict__ gamma, const float* __restrict__ beta,
    const ushort* __restrict__ addB, float* __restrict__ dstF,
    ushort* __restrict__ dstB, ushort* __restrict__ xTout, int mode)
{
    __shared__ float scs[64], shs[64];
    __shared__ ushort lt[128*72];
    const int bid = blockIdx.x, t = threadIdx.x;
    const int b = bid>>7, y = bid&127;
    if (t < 64){
        float sum=0.f, ssq=0.f;
#pragma unroll
        for (int s=0;s<8;s++){ sum += statsL[s*128+t]; ssq += statsL[s*128+64+t]; }
        float mean = sum*(1.f/65536.f);
        float var  = ssq*(1.f/65536.f) - mean*mean;
        float inv  = rsqrtf(var + 1e-5f);
        float sc = gamma[t]*inv;
        scs[t] = sc; shs[t] = beta[t] - mean*sc;
    }
    __syncthreads();
#pragma unroll
    for (int i=0;i<4;i++){
        int g = i*256 + t;
        int ch = g>>4, xg = (g&15)*8;
        long base = (long)(((b<<6)+ch)<<14) + (y<<7) + xg;
        short8v v8 = *(const short8v*)(yv + base);
        float sc = scs[ch], sh = shs[ch];
        float r[8];
#pragma unroll
        for (int e=0;e<8;e++) r[e] = fmaxf(bf2f((ushort)v8[e])*sc+sh, 0.f);
        if (mode & 2) {
            short8v a8 = *(const short8v*)(addB + base);
#pragma unroll
            for (int e=0;e<8;e++) r[e] += bf2f((ushort)a8[e]);
        }
        if (mode & 4) {
            const float4* op = (const float4*)(dstF + base);
            float4 a0 = op[0], a1 = op[1];
            r[0]+=a0.x; r[1]+=a0.y; r[2]+=a0.z; r[3]+=a0.w;
            r[4]+=a1.x; r[5]+=a1.y; r[6]+=a1.z; r[7]+=a1.w;
        }
        if (mode & 5) {
            float4* dp = (float4*)(dstF + base);
            dp[0] = make_float4(r[0],r[1],r[2],r[3]);
            dp[1] = make_float4(r[4],r[5],r[6],r[7]);
        }
        if (mode & 16) {
            short8v o8;
#pragma unroll
            for (int e=0;e<8;e++) o8[e] = (short)f2bf(r[e]);
            *(short8v*)(dstB + base) = o8;
        }
        if (mode & 8) {
#pragma unroll
            for (int e=0;e<8;e++) lt[(xg+e)*72 + ch] = f2bf(r[e]);
        }
    }
    if (mode & 8) {
        __syncthreads();
        ushort* dp = xTout + (((b<<7)+y)<<13);
#pragma unroll
        for (int i=0;i<4;i++){
            int u = i*256 + t;
            int xx = u>>3, cg = u&7;
            short8v v8 = *(const short8v*)(lt + xx*72 + cg*8);
            *(short8v*)(dp + (xx<<6) + cg*8) = v8;
        }
    }
}

// ---------------- final merge: out = relu(ya) + relu(yb) + relu(yc) ----------------
__global__ __launch_bounds__(256) void norm3(
    const ushort* __restrict__ ya, const ushort* __restrict__ ybp,
    const ushort* __restrict__ yc, const float* __restrict__ statsG,
    const float* __restrict__ gamma, const float* __restrict__ beta,
    int la, int lb, int lc, float* __restrict__ out)
{
    __shared__ float sc3[3][64], sh3[3][64];
    const int bid = blockIdx.x, t = threadIdx.x;
    const int b = bid>>7, y = bid&127;
    if (t < 192){
        int set = t>>6, ch = t&63;
        int l = (set==0)? la : ((set==1)? lb : lc);
        const float* st = statsG + l*1024;
        float sum=0.f, ssq=0.f;
#pragma unroll
        for (int s=0;s<8;s++){ sum += st[s*128+ch]; ssq += st[s*128+64+ch]; }
        float mean = sum*(1.f/65536.f);
        float var  = ssq*(1.f/65536.f) - mean*mean;
        float inv  = rsqrtf(var + 1e-5f);
        float sc = gamma[l*64+ch]*inv;
        sc3[set][ch] = sc; sh3[set][ch] = beta[l*64+ch] - mean*sc;
    }
    __syncthreads();
#pragma unroll
    for (int i=0;i<4;i++){
        int g = i*256 + t;
        int ch = g>>4, xg = (g&15)*8;
        long base = (long)(((b<<6)+ch)<<14) + (y<<7) + xg;
        short8v a8 = *(const short8v*)(ya  + base);
        short8v b8 = *(const short8v*)(ybp + base);
        short8v c8 = *(const short8v*)(yc  + base);
        float sa = sc3[0][ch], ha = sh3[0][ch];
        float sb = sc3[1][ch], hb = sh3[1][ch];
        float sc = sc3[2][ch], hc = sh3[2][ch];
        float r[8];
#pragma unroll
        for (int e=0;e<8;e++)
            r[e] = fmaxf(bf2f((ushort)a8[e])*sa+ha, 0.f)
                 + fmaxf(bf2f((ushort)b8[e])*sb+hb, 0.f)
                 + fmaxf(bf2f((ushort)c8[e])*sc+hc, 0.f);
        float4* dp = (float4*)(out + base);
        dp[0] = make_float4(r[0],r[1],r[2],r[3]);
        dp[1] = make_float4(r[4],r[5],r[6],r[7]);
    }
}

// ---------------- host orchestration ----------------
extern "C" void kernel_launch(void* const* d_in, const int* in_sizes, int n_in,
                              void* d_out, int out_size, void* d_ws, size_t ws_size,
                              hipStream_t stream)
{
    const float* x  = (const float*)d_in[0];
    const float* ow = (const float*)d_in[1];
    const float* ob = (const float*)d_in[2];
    const float* dw = (const float*)d_in[3];
    const float* g  = (const float*)d_in[4];
    const float* be = (const float*)d_in[5];
    float* out = (float*)d_out;

    ushort* yb0    = (ushort*)d_ws;
    ushort* yb1    = yb0 + NTOT;
    ushort* t4b    = yb1 + NTOT;
    ushort* xA     = t4b + NTOT;
    ushort* xB     = xA + NTOT;
    float*  statsG = (float*)(xB + NTOT);
    ushort* dwPk   = (ushort*)(statsG + 7*1024);
    ushort* owPk   = dwPk + 286720;

    pack_w<<<1120, 256, 0, stream>>>(dw, ow, dwPk, owPk, statsG);
    transpose_x<<<512, 256, 0, stream>>>(x, xA);

    auto nf = [&](int l, const ushort* ybp, int mode, const ushort* addB,
                  float* dstF, ushort* dstB, ushort* xout){
        norm_fuse<<<512, 256, 0, stream>>>(ybp, statsG + l*1024, g + l*64, be + l*64,
                                           addB, dstF, dstB, xout, mode);
    };

    // pair {L4,L0} (both read x)
    dcn_layer<<<512, 512, 0, stream>>>(xA, xA, owPk, ob, dwPk, yb0, yb1, statsG, 4, 0);
    nf(4, yb0,       16, nullptr, nullptr, t4b,    nullptr);  // t4b = relu(L4(x)) bf16
    nf(0, yb1,        8, nullptr, nullptr, nullptr, xB);      // xB  = T(relu(L0(x)))
    // single L1
    dcn_layer<<<256, 512, 0, stream>>>(xB, xB, owPk, ob, dwPk, yb0, yb0, statsG, 1, 1);
    nf(1, yb0,       10, t4b,    nullptr, nullptr, xA);       // xA = T(relu(L1)+t4b) = s
    // pair {L2,L5} (both read s)
    dcn_layer<<<512, 512, 0, stream>>>(xA, xA, owPk, ob, dwPk, yb0, yb1, statsG, 2, 5);
    nf(2, yb0,        8, nullptr, nullptr, nullptr, xB);      // xB = T(relu(L2(s)))
    // pair {L3,L6}: L3 reads xB -> yb0 (y2 dead); L6 reads s -> t4b (dead)
    dcn_layer<<<512, 512, 0, stream>>>(xB, xA, owPk, ob, dwPk, yb0, t4b, statsG, 3, 6);
    // out = relu(L3) + relu(L5) + relu(L6)  (single pass, no RMW chain)
    norm3<<<512, 256, 0, stream>>>(yb0, yb1, t4b, statsG, g, be, 3, 5, 6, out);
}

// Round 21
// 267.153 us; speedup vs baseline: 1.1700x; 1.1700x over previous
//
#include <hip/hip_runtime.h>
#include <hip/hip_bf16.h>
#include <hip/hip_fp16.h>

#define NTOT 4194304
#define XSLAB 1271808          // 138*144*64 per batch (padded channel-last)
typedef __attribute__((ext_vector_type(4)))  short short4v;
typedef __attribute__((ext_vector_type(8)))  short short8v;
typedef __attribute__((ext_vector_type(4)))  float f32x4;
typedef __attribute__((ext_vector_type(2)))  float fx2;
typedef __attribute__((ext_vector_type(4)))  unsigned int uint4v;

__device__ __forceinline__ ushort f2bf(float f){
    __hip_bfloat16 h = __float2bfloat16(f);
    return __bfloat16_as_ushort(h);
}
__device__ __forceinline__ float bf2f(ushort u){
    return __uint_as_float(((unsigned)u)<<16);
}
__device__ __forceinline__ void gld_lds16(const ushort* g, char* l){
    __builtin_amdgcn_global_load_lds(
        (const __attribute__((address_space(1))) unsigned*)(g),
        (__attribute__((address_space(3))) unsigned*)(l), 16, 0, 0);
}

// ---------------- zero-fill padded xT buffers (borders stay 0 forever) ----------------
__global__ __launch_bounds__(256) void zero_fill(ushort* a, ushort* c){
    int i = blockIdx.x*256 + threadIdx.x;      // 635904 groups of 8
    const short8v z = (short8v){0,0,0,0,0,0,0,0};
    if (i < 4*XSLAB/8) { *(short8v*)(a + i*8) = z; *(short8v*)(c + i*8) = z; }
}

// ---------------- weight pack: per-lane MFMA B-fragment order, bf16 ----------------
__global__ __launch_bounds__(256) void pack_w(
    const float* __restrict__ dw, const float* __restrict__ ow,
    ushort* __restrict__ dwPk, ushort* __restrict__ owPk,
    float* __restrict__ statsG)
{
    int i = blockIdx.x*256 + threadIdx.x;
    if (i < 286720) {
        int j = i&3, co = (i>>2)&63, jg=(i>>8)&1, cih=(i>>9)&1, koff=(i>>10)&1;
        int r = i>>11; int kkp = r%5; int r2 = r/5; int ciq = r2&3; int l = r2>>2;
        int kk = kkp*2+koff, ci = ciq*16 + cih*8 + jg*4 + j;
        float v = (kk<9)? dw[((l*64+co)*64+ci)*9+kk] : 0.f;
        dwPk[i] = f2bf(v);
    }
    if (i < 143360) {
        int j = i&3, co = (i>>2)&31, jg=(i>>7)&1, cih=(i>>8)&1, koff=(i>>9)&1;
        int r = i>>10; int kkp = r%5; int r2 = r/5; int ciq = r2&3; int l = r2>>2;
        int kk = kkp*2+koff, ci = ciq*16 + cih*8 + jg*4 + j;
        float v = (kk<9 && co<18)? ow[((l*18+co)*64+ci)*9+kk] : 0.f;
        owPk[i] = f2bf(v);
    }
    if (i < 7*1024) statsG[i] = 0.f;
}

// ---------------- one-time transpose: NCHW f32 -> padded [b][y+5][x+8][ci] bf16 ----------------
__global__ __launch_bounds__(256) void transpose_x(
    const float* __restrict__ src, ushort* __restrict__ xT)
{
    __shared__ ushort lds[128*72];
    const int bid = blockIdx.x, t = threadIdx.x;
    const int b = bid>>7, y = bid&127;
    const float* sp = src + (b<<20) + (y<<7);
#pragma unroll
    for (int i=0;i<32;i++){
        int lin = i*256 + t;
        int ci = lin>>7, xx = lin&127;
        lds[xx*72 + ci] = f2bf(sp[(ci<<14) + xx]);
    }
    __syncthreads();
    ushort* dp = xT + (size_t)b*XSLAB + (((y+5)*144 + 8)<<6);
#pragma unroll
    for (int i=0;i<4;i++){
        int u = i*256 + t;
        int xx = u>>3, cg = u&7;
        short8v v8 = *(const short8v*)(lds + xx*72 + cg*8);
        *(short8v*)(dp + (xx<<6) + cg*8) = v8;
    }
}

__constant__ int KHt[10] = {0,0,0,1,1,1,2,2,2,2};
__constant__ int KWt[10] = {0,1,2,0,1,2,0,1,2,2};

// ---------------- fused offset-conv + deformable conv ----------------
// r19 structure (best: staged pass 1 + pass 2, hoisted bilinear, lazy masking,
// pk_fma interp, pair dispatch). Staging upgraded:
//  - padded xT: no bounds checks/clamps/selects in stage (borders are real zeros)
//  - global_load_lds width=16, linear LDS dest (64B rows), swizzle moved into
//    PRE-SWIZZLED global source: phys unit g holds logical u = g ^ ((sp>>1)&3)
//    (16 consecutive sp -> 8 distinct 16B slots -> 2-way = free on read).
__global__ __attribute__((amdgpu_flat_work_group_size(512,512), amdgpu_waves_per_eu(4,8)))
void dcn_layer(
    const ushort* __restrict__ xTA, const ushort* __restrict__ xTB,
    const ushort* __restrict__ owPkB, const float* __restrict__ obB,
    const ushort* __restrict__ dwPkB, ushort* __restrict__ ybA,
    ushort* __restrict__ ybX, float* __restrict__ statsB, int l0, int l1)
{
    __shared__ __align__(16) char smem[65536];
    __half* offh = (__half*)(smem + 55296);      // [256 px][20] fp16

    const int t = threadIdx.x, lane = t&63, w = t>>6;
    const int l15 = lane&15, lg = lane>>4;
    const int cih = lg&1, koff = lane>>5;
    const int bid = blockIdx.x;
    const int lsel = bid >> 8;
    const int tb = bid & 255;
    const int L = lsel ? l1 : l0;
    const ushort* owPk = owPkB + L*20480;
    const float*  ob   = obB   + L*18;
    const ushort* dwPk = dwPkB + L*40960;
    ushort* yb         = lsel ? ybX : ybA;
    float*  statsL     = statsB + L*1024;

    const int xcd = tb&7, idx = tb>>3;
    const int b = xcd>>1, vh = xcd&1;
    const int ht = vh*8 + (idx>>2), wt = idx&3;
    const int w0 = wt*32, h0 = ht*8;
    const int row = h0 + w;
    const int RLO = h0-5, CLO = w0-8;            // 18 x 48 halo
    const ushort* xb = (lsel ? xTB : xTA) + (size_t)b*XSLAB;

    // stage phase P: 3456 x 16B via global_load_lds, pre-swizzled source
    auto stage = [&](int P){
#pragma unroll 1
        for (int i=0;i<7;i++){
            int d = i*512 + t;
            if (d < 3456) {
                int sp = d>>2, gph = d&3;
                int rowt = sp/48, colt = sp - rowt*48;
                int gy = RLO+rowt, gx = CLO+colt;          // always in padded range
                int usrc = gph ^ ((sp>>1)&3);
                const ushort* gp = xb + ((((gy+5)*144 + (gx+8))<<6) + (P*4+usrc)*8);
                gld_lds16(gp, smem + ((i*512 + (t & ~63))<<4));
            }
        }
    };

    // ================= pass 1: offset conv via MFMA (A from LDS) =================
    f32x4 oacc[2][2];
#pragma unroll
    for (int p=0;p<2;p++)
#pragma unroll
        for (int q=0;q<2;q++) oacc[p][q] = (f32x4){0.f,0.f,0.f,0.f};

#pragma unroll 1
    for (int P=0; P<2; ++P) {
        if (P) __syncthreads();
        stage(P);
        __syncthreads();
#pragma unroll 1
        for (int kkp=0; kkp<5; ++kkp) {
            int kkA = 2*kkp;
            int kkB2 = (kkA+1>8)?8:(kkA+1);
            int kh = koff ? KHt[kkB2] : KHt[kkA];
            int kw = koff ? KWt[kkB2] : KWt[kkA];
            int PC[2], M4[2];
#pragma unroll
            for (int p=0;p<2;p++){
                int sp = (w + kh + 4)*48 + (p*16 + l15 + kw + 7);
                PC[p] = sp<<6; M4[p] = ((sp>>1)&3)<<4;
            }
#pragma unroll
            for (int cil=0; cil<2; ++cil) {
                int u4 = (((cil<<1)|cih)<<4);
                short8v afr[2];
#pragma unroll
                for (int p=0;p<2;p++)
                    afr[p] = *(const short8v*)(smem + PC[p] + (u4 ^ M4[p]));
                const ushort* wop = owPk + (P*2+cil)*5120 + kkp*1024 + koff*512 + cih*256;
#pragma unroll
                for (int q=0;q<2;q++){
                    short4v b0 = *(const short4v*)(wop +       (q*16+l15)*4);
                    short4v b1 = *(const short4v*)(wop + 128 + (q*16+l15)*4);
                    short8v bb = __builtin_shufflevector(b0,b1,0,1,2,3,4,5,6,7);
#pragma unroll
                    for (int p=0;p<2;p++)
                        oacc[p][q] = __builtin_amdgcn_mfma_f32_16x16x32_bf16(afr[p], bb, oacc[p][q], 0,0,0);
                }
            }
        }
    }

    // redistribute offsets fp16: offh[pix 256][20]; only o<18
    {
        float biasq[2];
#pragma unroll
        for (int q=0;q<2;q++){ int o = q*16+l15; biasq[q] = (o<18)? ob[o] : 0.f; }
#pragma unroll
        for (int p=0;p<2;p++)
#pragma unroll
            for (int q=0;q<2;q++){
                int o = q*16+l15;
                if (o < 18) {
#pragma unroll
                    for (int r=0;r<4;r++){
                        int pix = w*32 + p*16 + lg*4 + r;
                        offh[pix*20 + o] = __float2half(oacc[p][q][r] + biasq[q]);
                    }
                }
            }
    }

    // ================= pass 2: deformable conv via MFMA =================
    f32x4 acc[2][4];
#pragma unroll
    for (int p=0;p<2;p++)
#pragma unroll
        for (int q=0;q<4;q++) acc[p][q] = (f32x4){0.f,0.f,0.f,0.f};

#pragma unroll 1
    for (int P=0; P<2; ++P) {
        __syncthreads();   // P0: pass1 tile reads + offh writes done; P1: P0 reads done
        stage(P);
        __syncthreads();
#pragma unroll 1
        for (int kkp=0; kkp<5; ++kkp) {
            int kkA = 2*kkp;
            int kkB2 = (kkA+1>8)?8:(kkA+1);
            int kh = koff ? KHt[kkB2] : KHt[kkA];
            int kw = koff ? KWt[kkB2] : KWt[kkA];
            int kkX = koff ? kkB2 : kkA;
            // ---- hoisted bilinear setup (shared by both cil) ----
            float F00[2],F01[2],F10[2],F11[2];
            int PC0[2],PC1[2],PC2[2],PC3[2], M40[2],M41[2],M42[2],M43[2];
            bool FB[2];
#pragma unroll
            for (int p=0;p<2;p++){
                int pix = w*32 + p*16 + l15;
                unsigned odp = *(const unsigned*)((const char*)offh + pix*40 + 4*kkX);
                float dy = __half2float(__ushort_as_half((ushort)(odp & 0xffffu)));
                float dx = __half2float(__ushort_as_half((ushort)(odp >> 16)));
                float py = (float)(row + kh - 1) + dy;
                float px = (float)(w0 + p*16 + l15 + kw - 1) + dx;
                float fy = floorf(py), fx = floorf(px);
                float ly = py - fy, lx = px - fx;
                int y0 = (int)fy, x0 = (int)fx;
                int r0 = y0 - RLO, c0 = x0 - CLO;
                int r1 = r0 + 1,  c1 = c0 + 1;
                bool ty0 = ((unsigned)r0<18u), ty1 = ((unsigned)r1<18u);
                bool tx0 = ((unsigned)c0<48u), tx1 = ((unsigned)c1<48u);
                float w00 = (1.f-ly)*(1.f-lx), w01 = (1.f-ly)*lx;
                float w10 = ly*(1.f-lx),       w11 = ly*lx;
                F00[p] = (ty0&&tx0)? w00 : 0.f;
                F01[p] = (ty0&&tx1)? w01 : 0.f;
                F10[p] = (ty1&&tx0)? w10 : 0.f;
                F11[p] = (ty1&&tx1)? w11 : 0.f;
                int rc0 = min(max(r0,0),17), rc1 = min(max(r1,0),17);
                int xc0 = min(max(c0,0),47), xc1 = min(max(c1,0),47);
                int s00 = rc0*48+xc0, s01 = rc0*48+xc1, s10 = rc1*48+xc0, s11 = rc1*48+xc1;
                PC0[p]=s00<<6; M40[p]=((s00>>1)&3)<<4;
                PC1[p]=s01<<6; M41[p]=((s01>>1)&3)<<4;
                PC2[p]=s10<<6; M42[p]=((s10>>1)&3)<<4;
                PC3[p]=s11<<6; M43[p]=((s11>>1)&3)<<4;
                bool allIn = ty0 && ty1 && tx0 && tx1;
                FB[p] = !allIn && (y0>=-1)&&(y0<=127)&&(x0>=-1)&&(x0<=127);
            }
#pragma unroll
            for (int cil=0; cil<2; ++cil) {
                int ciq = P*2 + cil;
                int u4 = (((cil<<1)|cih)<<4);
                short8v afr[2];
#pragma unroll
                for (int p=0;p<2;p++){
                    uint4v q00 = *(const uint4v*)(smem + PC0[p] + (u4^M40[p]));
                    uint4v q01 = *(const uint4v*)(smem + PC1[p] + (u4^M41[p]));
                    uint4v q10 = *(const uint4v*)(smem + PC2[p] + (u4^M42[p]));
                    uint4v q11 = *(const uint4v*)(smem + PC3[p] + (u4^M43[p]));
                    fx2 Fa = {F00[p],F00[p]}, Fb = {F01[p],F01[p]};
                    fx2 Fc = {F10[p],F10[p]}, Fd = {F11[p],F11[p]};
                    fx2 sv2[4];
#pragma unroll
                    for (int k=0;k<4;k++){
                        fx2 xa = {__uint_as_float(q00[k]<<16), __uint_as_float(q00[k]&0xffff0000u)};
                        fx2 xb2= {__uint_as_float(q01[k]<<16), __uint_as_float(q01[k]&0xffff0000u)};
                        fx2 xc = {__uint_as_float(q10[k]<<16), __uint_as_float(q10[k]&0xffff0000u)};
                        fx2 xd = {__uint_as_float(q11[k]<<16), __uint_as_float(q11[k]&0xffff0000u)};
                        sv2[k] = xa*Fa + xb2*Fb + xc*Fc + xd*Fd;   // v_pk_fma_f32
                    }
                    if (__builtin_expect(FB[p], 0)) {
                        // rare out-of-tile: recompute locally (execz-skipped), padded xT
                        int pix = w*32 + p*16 + l15;
                        unsigned odp = *(const unsigned*)((const char*)offh + pix*40 + 4*kkX);
                        float dy = __half2float(__ushort_as_half((ushort)(odp & 0xffffu)));
                        float dx = __half2float(__ushort_as_half((ushort)(odp >> 16)));
                        float py = (float)(row + kh - 1) + dy;
                        float px = (float)(w0 + p*16 + l15 + kw - 1) + dx;
                        float fy = floorf(py), fx = floorf(px);
                        float ly = py - fy, lx = px - fx;
                        int y0 = (int)fy, x0 = (int)fx;
                        int r0 = y0 - RLO, c0 = x0 - CLO;
                        bool ty0 = ((unsigned)r0<18u), ty1 = ((unsigned)(r0+1)<18u);
                        bool tx0 = ((unsigned)c0<48u), tx1 = ((unsigned)(c0+1)<48u);
                        bool vy0 = ((unsigned)y0<128u), vy1 = ((unsigned)(y0+1)<128u);
                        bool vx0 = ((unsigned)x0<128u), vx1 = ((unsigned)(x0+1)<128u);
                        float w00 = (1.f-ly)*(1.f-lx), w01 = (1.f-ly)*lx;
                        float w10 = ly*(1.f-lx),       w11 = ly*lx;
                        float rw00 = (vy0&&vx0&&!(ty0&&tx0))? w00 : 0.f;
                        float rw01 = (vy0&&vx1&&!(ty0&&tx1))? w01 : 0.f;
                        float rw10 = (vy1&&vx0&&!(ty1&&tx0))? w10 : 0.f;
                        float rw11 = (vy1&&vx1&&!(ty1&&tx1))? w11 : 0.f;
                        int y0c=min(max(y0,0),127), y1c=min(max(y0+1,0),127);
                        int x0c=min(max(x0,0),127), x1c=min(max(x0+1,0),127);
                        int cofs = ciq*16 + cih*8;
                        short8v a0 = *(const short8v*)(xb + ((((y0c+5)*144+(x0c+8))<<6) + cofs));
                        short8v a1 = *(const short8v*)(xb + ((((y0c+5)*144+(x1c+8))<<6) + cofs));
                        short8v a2 = *(const short8v*)(xb + ((((y1c+5)*144+(x0c+8))<<6) + cofs));
                        short8v a3 = *(const short8v*)(xb + ((((y1c+5)*144+(x1c+8))<<6) + cofs));
#pragma unroll
                        for (int j=0;j<8;j++){
                            float add = rw00*bf2f((ushort)a0[j]) + rw01*bf2f((ushort)a1[j])
                                      + rw10*bf2f((ushort)a2[j]) + rw11*bf2f((ushort)a3[j]);
                            if (j&1) sv2[j>>1].y += add; else sv2[j>>1].x += add;
                        }
                    }
#pragma unroll
                    for (int k=0;k<4;k++){
                        afr[p][2*k]   = (short)f2bf(sv2[k].x);
                        afr[p][2*k+1] = (short)f2bf(sv2[k].y);
                    }
                }
                const ushort* wp = dwPk + ciq*10240 + kkp*2048 + koff*1024 + cih*512;
#pragma unroll
                for (int q=0;q<4;q++){
                    short4v b0 = *(const short4v*)(wp +       (q*16+l15)*4);
                    short4v b1 = *(const short4v*)(wp + 256 + (q*16+l15)*4);
                    short8v bb = __builtin_shufflevector(b0,b1,0,1,2,3,4,5,6,7);
                    acc[0][q] = __builtin_amdgcn_mfma_f32_16x16x32_bf16(afr[0], bb, acc[0][q], 0,0,0);
                    acc[1][q] = __builtin_amdgcn_mfma_f32_16x16x32_bf16(afr[1], bb, acc[1][q], 0,0,0);
                }
            }
        }
    }

    // ================= epilogue: LDS transpose, bf16 store, stats =================
    float* yt  = (float*)smem;               // [32 co][260] f32 (overlays tile)
    float* red = (float*)(smem + 33280);     // 1024 f32
#pragma unroll
    for (int half=0; half<2; ++half){
        __syncthreads();
#pragma unroll
        for (int p=0;p<2;p++)
#pragma unroll
            for (int qq=0;qq<2;qq++)
                *(f32x4*)(yt + (qq*16+l15)*260 + w*32 + p*16 + lg*4) = acc[p][half*2+qq];
        __syncthreads();
#pragma unroll
        for (int i=0;i<2;i++){
            int u = i*512 + t;
            int co = u>>5, px8 = (u&31)*8;
            short8v v8;
#pragma unroll
            for (int e=0;e<8;e++) v8[e] = (short)f2bf(yt[co*260 + px8 + e]);
            *(short8v*)(yb + ((((b<<6) + half*32 + co)<<14)
                        + ((h0 + (px8>>5))<<7) + w0 + (px8&31))) = v8;
        }
        {
            float s=0.f, s2=0.f;
            int co = t&31, seg = t>>5;
            const float* bp = yt + co*260 + seg*16;
#pragma unroll
            for (int qd=0;qd<16;qd++){ float v = bp[qd]; s += v; s2 += v*v; }
            red[seg*32+co] = s; red[512 + seg*32+co] = s2;
        }
        __syncthreads();
        if (t < 64){
            int vv = t>>5, cc = t&31;
            float a = 0.f;
#pragma unroll
            for (int g=0;g<16;g++) a += red[vv*512 + g*32 + cc];
            atomicAdd(statsL + (tb&7)*128 + vv*64 + half*32 + cc, a);
        }
    }
}

// ---------------- fused normalize + ReLU + epilogue + padded xT emission ----------------
// mode bits: 1=write dstF f32, 2=add addB (bf16 NCHW), 4=accum dstF f32,
//            8=emit xT (padded), 16=write dstB (bf16 NCHW).
__global__ __launch_bounds__(256) void norm_fuse(
    const ushort* __restrict__ yv, const float* __restrict__ statsL,
    const float* __restrict__ gamma, const float* __restrict__ beta,
    const ushort* __restrict__ addB, float* __restrict__ dstF,
    ushort* __restrict__ dstB, ushort* __restrict__ xTout, int mode)
{
    __shared__ float scs[64], shs[64];
    __shared__ ushort lt[128*72];
    const int bid = blockIdx.x, t = threadIdx.x;
    const int b = bid>>7, y = bid&127;
    if (t < 64){
        float sum=0.f, ssq=0.f;
#pragma unroll
        for (int s=0;s<8;s++){ sum += statsL[s*128+t]; ssq += statsL[s*128+64+t]; }
        float mean = sum*(1.f/65536.f);
        float var  = ssq*(1.f/65536.f) - mean*mean;
        float inv  = rsqrtf(var + 1e-5f);
        float sc = gamma[t]*inv;
        scs[t] = sc; shs[t] = beta[t] - mean*sc;
    }
    __syncthreads();
#pragma unroll
    for (int i=0;i<4;i++){
        int g = i*256 + t;
        int ch = g>>4, xg = (g&15)*8;
        long base = (long)(((b<<6)+ch)<<14) + (y<<7) + xg;
        short8v v8 = *(const short8v*)(yv + base);
        float sc = scs[ch], sh = shs[ch];
        float r[8];
#pragma unroll
        for (int e=0;e<8;e++) r[e] = fmaxf(bf2f((ushort)v8[e])*sc+sh, 0.f);
        if (mode & 2) {
            short8v a8 = *(const short8v*)(addB + base);
#pragma unroll
            for (int e=0;e<8;e++) r[e] += bf2f((ushort)a8[e]);
        }
        if (mode & 4) {
            const float4* op = (const float4*)(dstF + base);
            float4 a0 = op[0], a1 = op[1];
            r[0]+=a0.x; r[1]+=a0.y; r[2]+=a0.z; r[3]+=a0.w;
            r[4]+=a1.x; r[5]+=a1.y; r[6]+=a1.z; r[7]+=a1.w;
        }
        if (mode & 5) {
            float4* dp = (float4*)(dstF + base);
            dp[0] = make_float4(r[0],r[1],r[2],r[3]);
            dp[1] = make_float4(r[4],r[5],r[6],r[7]);
        }
        if (mode & 16) {
            short8v o8;
#pragma unroll
            for (int e=0;e<8;e++) o8[e] = (short)f2bf(r[e]);
            *(short8v*)(dstB + base) = o8;
        }
        if (mode & 8) {
#pragma unroll
            for (int e=0;e<8;e++) lt[(xg+e)*72 + ch] = f2bf(r[e]);
        }
    }
    if (mode & 8) {
        __syncthreads();
        ushort* dp = xTout + (size_t)b*XSLAB + (((y+5)*144 + 8)<<6);
#pragma unroll
        for (int i=0;i<4;i++){
            int u = i*256 + t;
            int xx = u>>3, cg = u&7;
            short8v v8 = *(const short8v*)(lt + xx*72 + cg*8);
            *(short8v*)(dp + (xx<<6) + cg*8) = v8;
        }
    }
}

// ---------------- final merge: out = relu(ya) + relu(yb) + relu(yc) ----------------
__global__ __launch_bounds__(256) void norm3(
    const ushort* __restrict__ ya, const ushort* __restrict__ ybp,
    const ushort* __restrict__ yc, const float* __restrict__ statsG,
    const float* __restrict__ gamma, const float* __restrict__ beta,
    int la, int lb, int lc, float* __restrict__ out)
{
    __shared__ float sc3[3][64], sh3[3][64];
    const int bid = blockIdx.x, t = threadIdx.x;
    const int b = bid>>7, y = bid&127;
    if (t < 192){
        int set = t>>6, ch = t&63;
        int l = (set==0)? la : ((set==1)? lb : lc);
        const float* st = statsG + l*1024;
        float sum=0.f, ssq=0.f;
#pragma unroll
        for (int s=0;s<8;s++){ sum += st[s*128+ch]; ssq += st[s*128+64+ch]; }
        float mean = sum*(1.f/65536.f);
        float var  = ssq*(1.f/65536.f) - mean*mean;
        float inv  = rsqrtf(var + 1e-5f);
        float sc = gamma[l*64+ch]*inv;
        sc3[set][ch] = sc; sh3[set][ch] = beta[l*64+ch] - mean*sc;
    }
    __syncthreads();
#pragma unroll
    for (int i=0;i<4;i++){
        int g = i*256 + t;
        int ch = g>>4, xg = (g&15)*8;
        long base = (long)(((b<<6)+ch)<<14) + (y<<7) + xg;
        short8v a8 = *(const short8v*)(ya  + base);
        short8v b8 = *(const short8v*)(ybp + base);
        short8v c8 = *(const short8v*)(yc  + base);
        float sa = sc3[0][ch], ha = sh3[0][ch];
        float sb = sc3[1][ch], hb = sh3[1][ch];
        float sc = sc3[2][ch], hc = sh3[2][ch];
        float r[8];
#pragma unroll
        for (int e=0;e<8;e++)
            r[e] = fmaxf(bf2f((ushort)a8[e])*sa+ha, 0.f)
                 + fmaxf(bf2f((ushort)b8[e])*sb+hb, 0.f)
                 + fmaxf(bf2f((ushort)c8[e])*sc+hc, 0.f);
        float4* dp = (float4*)(out + base);
        dp[0] = make_float4(r[0],r[1],r[2],r[3]);
        dp[1] = make_float4(r[4],r[5],r[6],r[7]);
    }
}

// ---------------- host orchestration ----------------
extern "C" void kernel_launch(void* const* d_in, const int* in_sizes, int n_in,
                              void* d_out, int out_size, void* d_ws, size_t ws_size,
                              hipStream_t stream)
{
    const float* x  = (const float*)d_in[0];
    const float* ow = (const float*)d_in[1];
    const float* ob = (const float*)d_in[2];
    const float* dw = (const float*)d_in[3];
    const float* g  = (const float*)d_in[4];
    const float* be = (const float*)d_in[5];
    float* out = (float*)d_out;

    ushort* yb0    = (ushort*)d_ws;
    ushort* yb1    = yb0 + NTOT;
    ushort* t4b    = yb1 + NTOT;
    ushort* xA     = t4b + NTOT;
    ushort* xB     = xA + 4*(size_t)XSLAB;
    float*  statsG = (float*)(xB + 4*(size_t)XSLAB);
    ushort* dwPk   = (ushort*)(statsG + 7*1024);
    ushort* owPk   = dwPk + 286720;

    zero_fill<<<2484, 256, 0, stream>>>(xA, xB);
    pack_w<<<1120, 256, 0, stream>>>(dw, ow, dwPk, owPk, statsG);
    transpose_x<<<512, 256, 0, stream>>>(x, xA);

    auto nf = [&](int l, const ushort* ybp, int mode, const ushort* addB,
                  float* dstF, ushort* dstB, ushort* xout){
        norm_fuse<<<512, 256, 0, stream>>>(ybp, statsG + l*1024, g + l*64, be + l*64,
                                           addB, dstF, dstB, xout, mode);
    };

    // pair {L4,L0} (both read x)
    dcn_layer<<<512, 512, 0, stream>>>(xA, xA, owPk, ob, dwPk, yb0, yb1, statsG, 4, 0);
    nf(4, yb0,       16, nullptr, nullptr, t4b,    nullptr);  // t4b = relu(L4(x)) bf16
    nf(0, yb1,        8, nullptr, nullptr, nullptr, xB);      // xB  = T(relu(L0(x)))
    // single L1
    dcn_layer<<<256, 512, 0, stream>>>(xB, xB, owPk, ob, dwPk, yb0, yb0, statsG, 1, 1);
    nf(1, yb0,       10, t4b,    nullptr, nullptr, xA);       // xA = T(relu(L1)+t4b) = s
    // pair {L2,L5} (both read s)
    dcn_layer<<<512, 512, 0, stream>>>(xA, xA, owPk, ob, dwPk, yb0, yb1, statsG, 2, 5);
    nf(2, yb0,        8, nullptr, nullptr, nullptr, xB);      // xB = T(relu(L2(s)))
    // pair {L3,L6}: L3 reads xB -> yb0; L6 reads s -> t4b (dead)
    dcn_layer<<<512, 512, 0, stream>>>(xB, xA, owPk, ob, dwPk, yb0, t4b, statsG, 3, 6);
    // out = relu(L3) + relu(L5) + relu(L6)
    norm3<<<512, 256, 0, stream>>>(yb0, yb1, t4b, statsG, g, be, 3, 5, 6, out);
}